// Round 2
// baseline (175.807 us; speedup 1.0000x reference)
//
#include <hip/hip_runtime.h>

// NeRF hierarchical inverse-CDF resampling — scatter formulation.
//
// One 64-lane wave per ray (NC==64). Lane j holds sigma[j], computes
// cdf[j] via wave scan. Because t_inv[i] = low + span*(i+1)/129 is affine
// in i, bin j owns the contiguous sample range [M_j, M_{j+1}) with
// M_j = floor(129*(cdf[j]-low)/span). Lane j scatter-writes its
// interpolation coefficients (A_j, B_j) into LDS for that range;
// each sample then evaluates t_fine = A + t_inv*B with one LDS read.
// No per-sample binary search, no per-sample division.

constexpr int NC = 64;
constexpr int NF = 128;
constexpr int WAVES_PER_BLOCK = 4;
constexpr int BLOCK = WAVES_PER_BLOCK * 64;

__global__ __launch_bounds__(BLOCK) void nerf_resample_kernel(
    const float* __restrict__ t_coarse,
    const float* __restrict__ sigma_coarse,
    float* __restrict__ out,
    int n_rays)
{
    __shared__ float2 ab[WAVES_PER_BLOCK][NF];

    const int lane = threadIdx.x & 63;
    const int wave = threadIdx.x >> 6;
    const int ray  = blockIdx.x * WAVES_PER_BLOCK + wave;
    if (ray >= n_rays) return;

    const size_t base = (size_t)ray * NC;

    // Coalesced: lane j reads sigma[ray][j].
    float s = sigma_coarse[base + lane];

    // Inclusive scan -> cdf in 'c'.
    float c = s;
    #pragma unroll
    for (int off = 1; off < 64; off <<= 1) {
        float n = __shfl_up(c, off, 64);
        if (lane >= off) c += n;
    }

    const float low  = __shfl(c, 0, 64);   // cdf[0]
    const float high = __shfl(c, 63, 64);  // cdf[NC-1]
    const float span = high - low;

    const float t0    = t_coarse[base];
    const float delta = t_coarse[base + 1] - t0;

    // M_j = #{ samples i : t_inv[i] <= cdf[j] } = floor(129*(cdf[j]-low)/span)
    const float idx_scale = 129.0f / span;
    int M = (int)floorf((c - low) * idx_scale);
    M = M < 0 ? 0 : (M > NF ? NF : M);
    if (lane == 63) M = NF;                // bin 63 never owns samples (== ref clip to 62)

    int end = __shfl_down(M, 1, 64);       // M_{j+1}
    if (lane == 63) end = NF;              // (empty: M==NF)

    // Interpolation coefficients: t_fine = A + t_inv * B for samples in bin j.
    //   B = delta / sigma[j+1];  A = t0 + j*delta - cdf[j]*B
    const float s1 = __shfl_down(s, 1, 64);      // sigma[j+1] (lane 63: unused)
    const float B  = delta / s1;
    const float A  = fmaf((float)lane, delta, t0) - c * B;

    float2* myb = ab[wave];
    for (int i = M; i < end; ++i)
        myb[i] = make_float2(A, B);
    // Same-wave LDS RAW: DS ops are in-order per wave; compiler emits the
    // lgkmcnt wait before the dependent reads below.

    float* orow = out + (size_t)ray * NF;
    #pragma unroll
    for (int k = 0; k < 2; ++k) {
        const int i = lane + k * 64;
        const float tinv = fmaf(span, (float)(i + 1) * (1.0f / 129.0f), low);
        const float2 v = myb[i];
        orow[i] = fmaf(tinv, v.y, v.x);    // coalesced 256B store
    }
}

extern "C" void kernel_launch(void* const* d_in, const int* in_sizes, int n_in,
                              void* d_out, int out_size, void* d_ws, size_t ws_size,
                              hipStream_t stream) {
    const float* t_coarse     = (const float*)d_in[0];
    const float* sigma_coarse = (const float*)d_in[1];
    float* out = (float*)d_out;

    const int n_rays = in_sizes[0] / NC;                       // 524288
    const int blocks = (n_rays + WAVES_PER_BLOCK - 1) / WAVES_PER_BLOCK;

    nerf_resample_kernel<<<blocks, BLOCK, 0, stream>>>(
        t_coarse, sigma_coarse, out, n_rays);
}

// Round 3
// 83.940 us; speedup vs baseline: 2.0944x; 2.0944x over previous
//
#include <hip/hip_runtime.h>

// NeRF hierarchical inverse-CDF resampling — 4 rays/wave, DPP scan, LDS scatter.
//
// Layout: wave64 = 4 rows of 16 lanes; row g handles ray (base+g). Lane q in a
// row holds sigma[ray][4q..4q+3] (one dwordx4 = 1KB/wave load). cdf via local
// 4-prefix + 4-step DPP row_shr scan (no LDS pipe, rays isolated by row
// boundaries). Bin j owns fine samples [floor(F_j), floor(F_{j+1})) with
// F_j = 129*(cdf_j-low)/span (affine t_inv); owner writes slot (cdf_j, B_j)
// to LDS, B = delta/sigma[j+1] with bin index j packed into B's low 6
// mantissa bits (rel err 7.5e-6 -> out err <= delta*7.5e-6). Eval:
// t = t_j + (tinv - cdf_j)*B, all lanes, coalesced float2 stores.

constexpr int NC = 64;
constexpr int NF = 128;
constexpr int RPW = 4;               // rays per wave
constexpr int WPB = 4;               // waves per block
constexpr int BLOCK = WPB * 64;
constexpr int RPB = WPB * RPW;       // 16 rays per block

template <int CTRL, bool BOUND>
__device__ __forceinline__ int dpp_mov_i(int x) {
    return __builtin_amdgcn_update_dpp(0, x, CTRL, 0xF, 0xF, BOUND);
}
template <int CTRL, bool BOUND>
__device__ __forceinline__ float dpp_mov_f(float x) {
    return __builtin_bit_cast(float,
        dpp_mov_i<CTRL, BOUND>(__builtin_bit_cast(int, x)));
}

__global__ __launch_bounds__(BLOCK) void nerf_resample_kernel(
    const float* __restrict__ t_coarse,
    const float* __restrict__ sigma_coarse,
    float* __restrict__ out,
    int n_rays)
{
    __shared__ alignas(16) float2 ab[WPB][RPW][NF];   // 16 KB/block

    const int lane = threadIdx.x & 63;
    const int wave = threadIdx.x >> 6;
    const int g    = lane >> 4;      // ray within wave (row index)
    const int q    = lane & 15;      // lane within row

    int ray = blockIdx.x * RPB + wave * RPW + g;
    if (ray >= n_rays) ray = n_rays - 1;     // tail: duplicate identical work

    const size_t base = (size_t)ray * NC;

    const float4 v  = *(const float4*)(sigma_coarse + base + 4 * q);
    const float2 tp = *(const float2*)(t_coarse + base);
    const float t0 = tp.x;
    const float dt = tp.y - tp.x;

    // local inclusive prefix over the 4 held sigmas
    const float p0 = v.x;
    const float p1 = p0 + v.y;
    const float p2 = p1 + v.z;
    const float p3 = p2 + v.w;

    // inclusive scan of p3 across the 16-lane row (DPP row_shr; rows = rays,
    // boundaries isolate rays; invalid source lanes contribute identity 0)
    float S = p3;
    S += dpp_mov_f<0x111, false>(S);   // row_shr:1
    S += dpp_mov_f<0x112, false>(S);   // row_shr:2
    S += dpp_mov_f<0x114, false>(S);   // row_shr:4
    S += dpp_mov_f<0x118, false>(S);   // row_shr:8
    const float E = S - p3;            // exclusive row offset

    const float c0 = E + p0;
    const float c1 = E + p1;
    const float c2 = E + p2;
    const float c3 = E + p3;

    // per-ray low/high broadcast within the row
    const int rowbase = lane & 48;
    const float low  = __shfl(c0, rowbase, 64);
    const float high = __shfl(c3, rowbase + 15, 64);
    const float span = high - low;
    const float kf = 129.0f * __builtin_amdgcn_rcpf(span);

    // sample-range starts per bin: M = floor((c-low)*k), monotone, >=0
    int M0 = (int)((c0 - low) * kf);
    int M1 = (int)((c1 - low) * kf);
    int M2 = (int)((c2 - low) * kf);
    int M3 = (int)((c3 - low) * kf);
    M0 = min(M0, NF); M1 = min(M1, NF); M2 = min(M2, NF); M3 = min(M3, NF);
    int   M4 = dpp_mov_i<0x101, true>(M0);     // next lane's M0 (row_shl:1)
    float sn = dpp_mov_f<0x101, true>(v.x);    // next lane's sigma[4q+4]
    if (q == 15) M4 = NF;                      // bin 63 owns nothing

    // coefficients: B = dt/sigma[j+1]; pack j into B's low 6 mantissa bits
    const float B0 = dt * __builtin_amdgcn_rcpf(v.y);
    const float B1 = dt * __builtin_amdgcn_rcpf(v.z);
    const float B2 = dt * __builtin_amdgcn_rcpf(v.w);
    const float B3 = dt * __builtin_amdgcn_rcpf(sn);
    const int jb = 4 * q;
    auto pack = [](float B, int j) -> float {
        unsigned b = __builtin_bit_cast(unsigned, B);
        return __builtin_bit_cast(float, (b & ~63u) | (unsigned)j);
    };
    const float2 sl0 = make_float2(c0, pack(B0, jb + 0));
    const float2 sl1 = make_float2(c1, pack(B1, jb + 1));
    const float2 sl2 = make_float2(c2, pack(B2, jb + 2));
    const float2 sl3 = make_float2(c3, pack(B3, jb + 3));

    float2* myb = ab[wave][g];
    for (int i = M0; i < M1; ++i) myb[i] = sl0;
    for (int i = M1; i < M2; ++i) myb[i] = sl1;
    for (int i = M2; i < M3; ++i) myb[i] = sl2;
    for (int i = M3; i < M4; ++i) myb[i] = sl3;
    // same-wave DS ordering: writes above are visible to the reads below
    // (in-order LDS pipe, no cross-wave sharing -> no __syncthreads needed)

    constexpr float u1 = 1.0f / 129.0f;
    const int ray0 = blockIdx.x * RPB + wave * RPW;
    #pragma unroll
    for (int r = 0; r < RPW; ++r) {
        // broadcast ray r's scalars (constant source lanes -> readlane)
        const float lo_r = __shfl(low,  16 * r, 64);
        const float sp_r = __shfl(span, 16 * r, 64);
        const float t0_r = __shfl(t0,   16 * r, 64);
        const float dt_r = __shfl(dt,   16 * r, 64);
        int ray_r = ray0 + r;
        if (ray_r >= n_rays) ray_r = n_rays - 1;

        // lane evaluates samples 2*lane, 2*lane+1 (one b128 LDS read)
        const float4 sv = *(const float4*)&ab[wave][r][2 * lane];
        const int i0 = 2 * lane;
        const float tinv0 = fmaf(sp_r, (float)(i0 + 1) * u1, lo_r);
        const float tinv1 = fmaf(sp_r, (float)(i0 + 2) * u1, lo_r);

        const int j0 = (int)(__builtin_bit_cast(unsigned, sv.y) & 63u);
        const int j1 = (int)(__builtin_bit_cast(unsigned, sv.w) & 63u);
        const float tj0 = fmaf((float)j0, dt_r, t0_r);
        const float tj1 = fmaf((float)j1, dt_r, t0_r);
        const float r0 = fmaf(tinv0 - sv.x, sv.y, tj0);
        const float r1 = fmaf(tinv1 - sv.z, sv.w, tj1);

        *(float2*)(out + (size_t)ray_r * NF + i0) = make_float2(r0, r1);
    }
}

extern "C" void kernel_launch(void* const* d_in, const int* in_sizes, int n_in,
                              void* d_out, int out_size, void* d_ws, size_t ws_size,
                              hipStream_t stream) {
    const float* t_coarse     = (const float*)d_in[0];
    const float* sigma_coarse = (const float*)d_in[1];
    float* out = (float*)d_out;

    const int n_rays = in_sizes[0] / NC;                 // 524288
    const int blocks = (n_rays + RPB - 1) / RPB;         // 32768

    nerf_resample_kernel<<<blocks, BLOCK, 0, stream>>>(
        t_coarse, sigma_coarse, out, n_rays);
}

// Round 5
// 71.620 us; speedup vs baseline: 2.4547x; 1.1720x over previous
//
#include <hip/hip_runtime.h>

// NeRF hierarchical inverse-CDF resampling — 4 rays/wave, DPP scan, LDS
// scatter, nontemporal dwordx4 stores.
//
// Wave64 = 4 rows of 16 lanes; row g owns ray (base+g). Lane q in a row
// holds sigma[ray][4q..4q+3] (one dwordx4 = 1KB/wave). cdf via local
// 4-prefix + 4-step DPP row_shr scan. Bin j owns fine samples
// [floor(F_j), floor(F_{j+1})), F_j = 129*(cdf_j-low)/span; owner writes
// (cdf_j, B_j) into LDS slots, B = dt/sigma[j+1] with bin index j packed
// into B's low 6 mantissa bits (rel err 7.5e-6). Eval: each 32-lane half
// evaluates 4 consecutive samples of one ray -> one b128 nt store.
// Output streamed via nontemporal stores so sigma stays L3-resident.

constexpr int NC = 64;
constexpr int NF = 128;
constexpr int RPW = 4;               // rays per wave
constexpr int WPB = 4;               // waves per block
constexpr int BLOCK = WPB * 64;
constexpr int RPB = WPB * RPW;       // 16 rays per block

typedef float f32x4 __attribute__((ext_vector_type(4)));   // native vec for nt-store

template <int CTRL, bool BOUND>
__device__ __forceinline__ int dpp_mov_i(int x) {
    return __builtin_amdgcn_update_dpp(0, x, CTRL, 0xF, 0xF, BOUND);
}
template <int CTRL, bool BOUND>
__device__ __forceinline__ float dpp_mov_f(float x) {
    return __builtin_bit_cast(float,
        dpp_mov_i<CTRL, BOUND>(__builtin_bit_cast(int, x)));
}

__global__ __launch_bounds__(BLOCK) void nerf_resample_kernel(
    const float* __restrict__ t_coarse,
    const float* __restrict__ sigma_coarse,
    float* __restrict__ out,
    int n_rays)
{
    __shared__ alignas(16) float2 ab[WPB][RPW][NF];   // 16 KB/block

    const int lane = threadIdx.x & 63;
    const int wave = threadIdx.x >> 6;
    const int g    = lane >> 4;      // ray within wave (row index)
    const int q    = lane & 15;      // lane within row

    int ray = blockIdx.x * RPB + wave * RPW + g;
    if (ray >= n_rays) ray = n_rays - 1;     // tail: duplicate identical work

    const size_t base = (size_t)ray * NC;

    const float4 v  = *(const float4*)(sigma_coarse + base + 4 * q);
    const float2 tp = *(const float2*)(t_coarse + base);
    const float t0 = tp.x;
    const float dt = tp.y - tp.x;

    // local inclusive prefix over the 4 held sigmas
    const float p0 = v.x;
    const float p1 = p0 + v.y;
    const float p2 = p1 + v.z;
    const float p3 = p2 + v.w;

    // inclusive scan of p3 across the 16-lane row (row_shr; rows = rays,
    // row boundaries isolate rays; invalid source lanes contribute 0)
    float S = p3;
    S += dpp_mov_f<0x111, false>(S);   // row_shr:1
    S += dpp_mov_f<0x112, false>(S);   // row_shr:2
    S += dpp_mov_f<0x114, false>(S);   // row_shr:4
    S += dpp_mov_f<0x118, false>(S);   // row_shr:8
    const float E = S - p3;            // exclusive row offset

    const float c0 = E + p0;
    const float c1 = E + p1;
    const float c2 = E + p2;
    const float c3 = E + p3;

    // per-ray low/high broadcast within the row
    const int rowbase = lane & 48;
    const float low  = __shfl(c0, rowbase, 64);
    const float high = __shfl(c3, rowbase + 15, 64);
    const float span = high - low;
    const float kf = 129.0f * __builtin_amdgcn_rcpf(span);

    // sample-range starts per bin: M = floor((c-low)*kf), monotone, >=0
    int M0 = (int)((c0 - low) * kf);
    int M1 = (int)((c1 - low) * kf);
    int M2 = (int)((c2 - low) * kf);
    int M3 = (int)((c3 - low) * kf);
    M0 = min(M0, NF); M1 = min(M1, NF); M2 = min(M2, NF); M3 = min(M3, NF);
    int   M4 = dpp_mov_i<0x101, true>(M0);     // next lane's M0 (row_shl:1)
    float sn = dpp_mov_f<0x101, true>(v.x);    // next lane's sigma[4q+4]
    if (q == 15) M4 = NF;                      // bin 63 owns nothing

    // coefficients: B = dt/sigma[j+1]; pack j into B's low 6 mantissa bits
    const float B0 = dt * __builtin_amdgcn_rcpf(v.y);
    const float B1 = dt * __builtin_amdgcn_rcpf(v.z);
    const float B2 = dt * __builtin_amdgcn_rcpf(v.w);
    const float B3 = dt * __builtin_amdgcn_rcpf(sn);
    const int jb = 4 * q;
    auto pack = [](float B, int j) -> float {
        unsigned b = __builtin_bit_cast(unsigned, B);
        return __builtin_bit_cast(float, (b & ~63u) | (unsigned)j);
    };
    const float2 sl0 = make_float2(c0, pack(B0, jb + 0));
    const float2 sl1 = make_float2(c1, pack(B1, jb + 1));
    const float2 sl2 = make_float2(c2, pack(B2, jb + 2));
    const float2 sl3 = make_float2(c3, pack(B3, jb + 3));

    float2* myb = ab[wave][g];
    for (int i = M0; i < M1; ++i) myb[i] = sl0;
    for (int i = M1; i < M2; ++i) myb[i] = sl1;
    for (int i = M2; i < M3; ++i) myb[i] = sl2;
    for (int i = M3; i < M4; ++i) myb[i] = sl3;
    // same-wave DS ordering: scatter writes visible to reads below without
    // __syncthreads (in-order LDS pipe, no cross-wave sharing)

    constexpr float u1 = 1.0f / 129.0f;
    const int ray0 = blockIdx.x * RPB + wave * RPW;
    const int half = lane >> 5;           // 0 or 1
    const int q2   = lane & 31;
    const int i0   = 4 * q2;              // sample base 0..124

    #pragma unroll
    for (int p = 0; p < 2; ++p) {
        const int rr   = 2 * p + half;    // ray-in-wave this half evaluates
        const int srcl = 16 * rr;         // its row-base lane
        const float lo_r = __shfl(low,  srcl, 64);
        const float sp_r = __shfl(span, srcl, 64);
        const float t0_r = __shfl(t0,   srcl, 64);
        const float dt_r = __shfl(dt,   srcl, 64);
        int ray_r = ray0 + rr;
        if (ray_r >= n_rays) ray_r = n_rays - 1;

        // slots i0..i0+3: two b128 LDS reads
        const float4 sa = *(const float4*)&ab[wave][rr][i0];
        const float4 sb = *(const float4*)&ab[wave][rr][i0 + 2];

        const float tinv0 = fmaf(sp_r, (float)(i0 + 1) * u1, lo_r);
        const float tinv1 = fmaf(sp_r, (float)(i0 + 2) * u1, lo_r);
        const float tinv2 = fmaf(sp_r, (float)(i0 + 3) * u1, lo_r);
        const float tinv3 = fmaf(sp_r, (float)(i0 + 4) * u1, lo_r);

        const int j0 = (int)(__builtin_bit_cast(unsigned, sa.y) & 63u);
        const int j1 = (int)(__builtin_bit_cast(unsigned, sa.w) & 63u);
        const int j2 = (int)(__builtin_bit_cast(unsigned, sb.y) & 63u);
        const int j3 = (int)(__builtin_bit_cast(unsigned, sb.w) & 63u);

        const float r0 = fmaf(tinv0 - sa.x, sa.y, fmaf((float)j0, dt_r, t0_r));
        const float r1 = fmaf(tinv1 - sa.z, sa.w, fmaf((float)j1, dt_r, t0_r));
        const float r2 = fmaf(tinv2 - sb.x, sb.y, fmaf((float)j2, dt_r, t0_r));
        const float r3 = fmaf(tinv3 - sb.z, sb.w, fmaf((float)j3, dt_r, t0_r));

        // nontemporal: stream past L2/L3 allocate so sigma stays cached
        f32x4 rv = { r0, r1, r2, r3 };
        __builtin_nontemporal_store(rv,
            (f32x4*)(out + (size_t)ray_r * NF + i0));
    }
}

extern "C" void kernel_launch(void* const* d_in, const int* in_sizes, int n_in,
                              void* d_out, int out_size, void* d_ws, size_t ws_size,
                              hipStream_t stream) {
    const float* t_coarse     = (const float*)d_in[0];
    const float* sigma_coarse = (const float*)d_in[1];
    float* out = (float*)d_out;

    const int n_rays = in_sizes[0] / NC;                 // 524288
    const int blocks = (n_rays + RPB - 1) / RPB;         // 32768

    nerf_resample_kernel<<<blocks, BLOCK, 0, stream>>>(
        t_coarse, sigma_coarse, out, n_rays);
}